// Round 11
// baseline (1468.806 us; speedup 1.0000x reference)
//
#include <hip/hip_runtime.h>
#include <math.h>

#define NB 16
#define T  2048
#define D  512
#define BD 64
#define BT (NB*T)  // 32768

// workspace layout (float offsets)
#define OFF_K   0
#define OFF_V   (BT*BD)
#define OFF_Q   (2*BT*BD)
#define OFF_ETA (3*BT*BD)
#define OFF_H   (3*BT*BD + BT)
// total floats = 4*BT*BD + BT = 8,421,376  (~33.7 MB)

// gram scratch lives in d_out (64 MB; overwritten later by outproj):
// per 16-step chunk: KK[16*16] | KQ[16*16] | SC[16] | pad -> 544 floats
#define GSTRIDE 544
#define NCHUNK  (BT/16)   // 2048

#define RL(x, i) __int_as_float(__builtin_amdgcn_readlane(__float_as_int(x), (i)))

// ---------------- DPP full-wave sum, result broadcast to all lanes ----------
__device__ __forceinline__ float wave_allsum(float x) {
  x += __int_as_float(__builtin_amdgcn_update_dpp(
      0, __float_as_int(x), 0x111, 0xf, 0xf, true));   // row_shr:1
  x += __int_as_float(__builtin_amdgcn_update_dpp(
      0, __float_as_int(x), 0x112, 0xf, 0xf, true));   // row_shr:2
  x += __int_as_float(__builtin_amdgcn_update_dpp(
      0, __float_as_int(x), 0x114, 0xf, 0xf, true));   // row_shr:4
  x += __int_as_float(__builtin_amdgcn_update_dpp(
      0, __float_as_int(x), 0x118, 0xf, 0xf, true));   // row_shr:8
  x += __int_as_float(__builtin_amdgcn_update_dpp(
      0, __float_as_int(x), 0x142, 0xa, 0xf, false));  // row_bcast:15 -> rows 1,3
  x += __int_as_float(__builtin_amdgcn_update_dpp(
      0, __float_as_int(x), 0x143, 0xc, 0xf, false));  // row_bcast:31 -> rows 2,3
  return RL(x, 63);
}

// DS-only barrier: waits lgkmcnt(0) (all loop lgkm ops are DS), leaves vmcnt
// in flight. Proven r3/r4.
__device__ __forceinline__ void lds_barrier() {
  __builtin_amdgcn_sched_barrier(0);
  __builtin_amdgcn_s_waitcnt(0xC07F);  // vmcnt=63 (no wait), expcnt=7, lgkmcnt=0
  __builtin_amdgcn_s_barrier();
  __builtin_amdgcn_sched_barrier(0);
}

// -------- fused projection + eta + gram ------------------------------------
// Round 15: occupancy fix. The r13/r14 version staged x in 32KB LDS ->
// 44.5KB/block -> 3 blocks/CU; the 12 L2-latency weight loads per d-iter
// were latency-starved at 3 waves/SIMD. The d-loop's x reads are
// wave-uniform (all 64 lanes read the same row values), so read x straight
// from global (L1 serves the 32KB block working set; identical float bits,
// identical FMA grouping). eta reverts to the verified standalone code
// (global x). LDS now 12.3KB -> 8 blocks/CU (wave cap); 2048 blocks = one
// co-resident grid wave.
__global__ __launch_bounds__(256) void proj_kernel(
    const float* __restrict__ x,
    const float* __restrict__ Wk, const float* __restrict__ bk,
    const float* __restrict__ Wv, const float* __restrict__ bv,
    const float* __restrict__ Wq, const float* __restrict__ bq,
    const float* __restrict__ lr_w, const float* __restrict__ lr_b,
    const float* __restrict__ ln_g, const float* __restrict__ ln_b,
    float* __restrict__ Kout, float* __restrict__ Vout,
    float* __restrict__ Qout, float* __restrict__ eta,
    float* __restrict__ G) {
  __shared__ __align__(16) float sK[16][64], sQ[16][64], sV[16][64];  // 12 KB
  __shared__ float sg[64], sb[64];
  const int tid = threadIdx.x;
  const size_t row0 = (size_t)blockIdx.x * 16;
  if (tid < 64) { sg[tid] = ln_g[tid]; sb[tid] = ln_b[tid]; }
  const int col = tid & 63;
  const int rg = tid >> 6;  // 4 row-groups of 4 rows
  const int lane = tid & 63;

  float ak0 = 0.f, ak1 = 0.f, ak2 = 0.f, ak3 = 0.f;
  float av0 = 0.f, av1 = 0.f, av2 = 0.f, av3 = 0.f;
  float aq0 = 0.f, aq1 = 0.f, aq2 = 0.f, aq3 = 0.f;
  const float* xrow = x + (row0 + (size_t)(rg * 4)) * D;
  for (int d = 0; d < D; d += 4) {
    float wk0 = Wk[(d + 0) * BD + col];
    float wk1 = Wk[(d + 1) * BD + col];
    float wk2 = Wk[(d + 2) * BD + col];
    float wk3 = Wk[(d + 3) * BD + col];
    float wv0 = Wv[(d + 0) * BD + col];
    float wv1 = Wv[(d + 1) * BD + col];
    float wv2 = Wv[(d + 2) * BD + col];
    float wv3 = Wv[(d + 3) * BD + col];
    float wq0 = Wq[(d + 0) * BD + col];
    float wq1 = Wq[(d + 1) * BD + col];
    float wq2 = Wq[(d + 2) * BD + col];
    float wq3 = Wq[(d + 3) * BD + col];
    float4 x0 = *(const float4*)(xrow + d);
    float4 x1 = *(const float4*)(xrow + D + d);
    float4 x2 = *(const float4*)(xrow + 2 * D + d);
    float4 x3 = *(const float4*)(xrow + 3 * D + d);
    ak0 += x0.x * wk0 + x0.y * wk1 + x0.z * wk2 + x0.w * wk3;
    ak1 += x1.x * wk0 + x1.y * wk1 + x1.z * wk2 + x1.w * wk3;
    ak2 += x2.x * wk0 + x2.y * wk1 + x2.z * wk2 + x2.w * wk3;
    ak3 += x3.x * wk0 + x3.y * wk1 + x3.z * wk2 + x3.w * wk3;
    av0 += x0.x * wv0 + x0.y * wv1 + x0.z * wv2 + x0.w * wv3;
    av1 += x1.x * wv0 + x1.y * wv1 + x1.z * wv2 + x1.w * wv3;
    av2 += x2.x * wv0 + x2.y * wv1 + x2.z * wv2 + x2.w * wv3;
    av3 += x3.x * wv0 + x3.y * wv1 + x3.z * wv2 + x3.w * wv3;
    aq0 += x0.x * wq0 + x0.y * wq1 + x0.z * wq2 + x0.w * wq3;
    aq1 += x1.x * wq0 + x1.y * wq1 + x1.z * wq2 + x1.w * wq3;
    aq2 += x2.x * wq0 + x2.y * wq1 + x2.z * wq2 + x2.w * wq3;
    aq3 += x3.x * wq0 + x3.y * wq1 + x3.z * wq2 + x3.w * wq3;
  }
  float bbk = bk[col], bbv = bv[col], bbq = bq[col];
  const size_t r0 = row0 + rg * 4;
  float k0v = ak0 + bbk, k1v = ak1 + bbk, k2v = ak2 + bbk, k3v = ak3 + bbk;
  float v0v = av0 + bbv, v1v = av1 + bbv, v2v = av2 + bbv, v3v = av3 + bbv;
  float q0v = aq0 + bbq, q1v = aq1 + bbq, q2v = aq2 + bbq, q3v = aq3 + bbq;
  Kout[(r0 + 0) * BD + col] = k0v;
  Kout[(r0 + 1) * BD + col] = k1v;
  Kout[(r0 + 2) * BD + col] = k2v;
  Kout[(r0 + 3) * BD + col] = k3v;
  Vout[(r0 + 0) * BD + col] = v0v;
  Vout[(r0 + 1) * BD + col] = v1v;
  Vout[(r0 + 2) * BD + col] = v2v;
  Vout[(r0 + 3) * BD + col] = v3v;
  Qout[(r0 + 0) * BD + col] = q0v;
  Qout[(r0 + 1) * BD + col] = q1v;
  Qout[(r0 + 2) * BD + col] = q2v;
  Qout[(r0 + 3) * BD + col] = q3v;
  // stage K/V/Q tile to LDS for the gram phase
  const int lr = rg * 4;
  sK[lr + 0][col] = k0v; sK[lr + 1][col] = k1v;
  sK[lr + 2][col] = k2v; sK[lr + 3][col] = k3v;
  sV[lr + 0][col] = v0v; sV[lr + 1][col] = v1v;
  sV[lr + 2][col] = v2v; sV[lr + 3][col] = v3v;
  sQ[lr + 0][col] = q0v; sQ[lr + 1][col] = q1v;
  sQ[lr + 2][col] = q2v; sQ[lr + 3][col] = q3v;

  // ---- eta for this wave's 4 rows (exact code of the verified standalone
  // eta_kernel; reads global x) ----
  {
    const float* lw = lr_w + lane * 8;
    float4 la = *(const float4*)lw;
    float4 lb = *(const float4*)(lw + 4);
    float lrb0 = lr_b[0];
#pragma unroll
    for (int j = 0; j < 4; j++) {
      const float* xr = x + (row0 + (size_t)(rg * 4 + j)) * D + lane * 8;
      float4 a = *(const float4*)xr;
      float4 b2 = *(const float4*)(xr + 4);
      float p = a.x * la.x + a.y * la.y + a.z * la.z + a.w * la.w +
                b2.x * lb.x + b2.y * lb.y + b2.z * lb.z + b2.w * lb.w;
#pragma unroll
      for (int m = 32; m > 0; m >>= 1) p += __shfl_xor(p, m, 64);
      if (lane == 0) eta[row0 + rg * 4 + j] = 1.0f / (1.0f + expf(-(p + lrb0)));
    }
  }
  __syncthreads();

  // ---- gram phase: bit-identical to the old standalone gram_kernel ----
  const int gi = tid >> 4, gt = tid & 15;
  float kk = 0.f, kq = 0.f;
#pragma unroll
  for (int d = 0; d < 64; d += 4) {
    float4 a4 = *(const float4*)&sK[gi][d];
    float4 b4 = *(const float4*)&sK[gt][d];
    float4 c4 = *(const float4*)&sQ[gt][d];
    kk += a4.x * b4.x + a4.y * b4.y + a4.z * b4.z + a4.w * b4.w;
    kq += a4.x * c4.x + a4.y * c4.y + a4.z * c4.z + a4.w * c4.w;
  }
  size_t gb = (size_t)blockIdx.x * GSTRIDE;
  G[gb + gi * 16 + gt] = kk;
  G[gb + 256 + gi * 16 + gt] = kq;
  if (tid < 16) {
    float sc = 0.f;
    for (int d = 0; d < 64; d++)
      sc += sg[d] * (sK[tid][d] + sb[d] - sV[tid][d]);
    G[gb + 512 + tid] = sc;
  }
}

// ---------------- sequential TTT scan: chunked delta-rule, 4 waves --------
// FROZEN: exact r4 structure, measured 1096/1096/1094/1095us across four
// runs. Five structural variants (r5-r8) all regressed; do not touch.
__global__ __launch_bounds__(256, 1)
void ttt_seq_kernel(
    const float* __restrict__ Kin, const float* __restrict__ Vin,
    const float* __restrict__ Qin, const float* __restrict__ eta_in,
    const float* __restrict__ W0, const float* __restrict__ ln_g,
    const float* __restrict__ ln_b, float* __restrict__ Hout,
    const float* __restrict__ gram) {
  __shared__ __align__(16) float2 part2[16][4][64];  // 32 KB partials
  __shared__ __align__(16) float kls[16][64];        // 4 KB k rows
  __shared__ __align__(16) float qls[16][64];        // 4 KB q rows
  const int tid = threadIdx.x;
  const int lane = tid & 63;
  const int wvu = __builtin_amdgcn_readfirstlane(tid) >> 6;
  const int b = blockIdx.x;

  // W slice: w[4i+j] = W0[lane*BD + 16*wvu + 4i+j]
  float w[16];
  {
    const float4* w04 = (const float4*)(W0 + (size_t)lane * BD + wvu * 16);
#pragma unroll
    for (int i = 0; i < 4; i++) {
      float4 t4 = w04[i];
      w[4 * i] = t4.x; w[4 * i + 1] = t4.y; w[4 * i + 2] = t4.z; w[4 * i + 3] = t4.w;
    }
  }
  const float g = ln_g[lane];
  const float bet = ln_b[lane];
  const float a = g * g;
  const float A2 = wave_allsum(a);

  size_t base = (size_t)b * T * BD;   // advances BD per step
  size_t ebase = (size_t)b * T;

  // per-lane rows of the current chunk (reloaded in-place for chunk+1 during
  // phase B, period-16 ring -> zero extra registers)
  float krow[16], qrow[16], vrow[16];
#pragma unroll
  for (int r = 0; r < 16; r++) {
    krow[r] = Kin[base + r * BD + lane];
    qrow[r] = Qin[base + r * BD + lane];
    vrow[r] = Vin[base + r * BD + lane];
  }
  float ev  = eta_in[ebase + lane];
  float evn = eta_in[ebase + 64 + lane];

  float u2sv[4], qsv[4];  // deferred phase-2 state (4 owned steps per wave)

  for (int c64 = 0; c64 < 32; c64++) {
    size_t eoff = (size_t)(c64 + 2) * 64;
    if (eoff >= T) eoff = 0;
    float ev2 = eta_in[ebase + eoff + lane];

    for (int cc = 0; cc < 4; cc++) {
      // ---- gram loads for this chunk (consumed in phase B; phase A covers) --
      const size_t gb = (size_t)(b * 128 + c64 * 4 + cc) * GSTRIDE;
      float KKr[15], KQr[16];
#pragma unroll
      for (int t = 0; t < 15; t++) KKr[t] = gram[gb + t * 16 + lane];
#pragma unroll
      for (int t = 0; t < 16; t++) KQr[t] = gram[gb + 256 + t * 16 + lane];
      float SCv = gram[gb + 512 + lane];

      // ---- phase A: stage rows to LDS (all waves write identical values:
      // benign; each wave's own in-order DS writes make its reads correct) --
#pragma unroll
      for (int r = 0; r < 16; r++) {
        kls[r][lane] = krow[r];
        qls[r][lane] = qrow[r];
      }
      // 3-deep uniform-read pipeline (broadcast ds_read_b128, conflict-free)
      float4 kuf[3][4], quf[3][4];
#pragma unroll
      for (int r = 0; r < 3; r++) {
        const float4* kp = (const float4*)&kls[r][wvu * 16];
        const float4* qp = (const float4*)&qls[r][wvu * 16];
#pragma unroll
        for (int i = 0; i < 4; i++) { kuf[r][i] = kp[i]; quf[r][i] = qp[i]; }
      }
      float u0[16], p0[16];
#pragma unroll
      for (int r = 0; r < 16; r++) {
        const int bf = r % 3;
        float uu0 = 0.f, uu1 = 0.f, uu2 = 0.f, uu3 = 0.f;
        float pp0 = 0.f, pp1 = 0.f, pp2 = 0.f, pp3 = 0.f;
#pragma unroll
        for (int i = 0; i < 4; i++) {
          uu0 += kuf[bf][i].x * w[4 * i + 0];
          uu1 += kuf[bf][i].y * w[4 * i + 1];
          uu2 += kuf[bf][i].z * w[4 * i + 2];
          uu3 += kuf[bf][i].w * w[4 * i + 3];
          pp0 += quf[bf][i].x * w[4 * i + 0];
          pp1 += quf[bf][i].y * w[4 * i + 1];
          pp2 += quf[bf][i].z * w[4 * i + 2];
          pp3 += quf[bf][i].w * w[4 * i + 3];
        }
        part2[r][wvu][lane] = make_float2((uu0 + uu1) + (uu2 + uu3),
                                          (pp0 + pp1) + (pp2 + pp3));
        if (r < 13) {
          const float4* kp = (const float4*)&kls[r + 3][wvu * 16];
          const float4* qp = (const float4*)&qls[r + 3][wvu * 16];
#pragma unroll
          for (int i = 0; i < 4; i++) { kuf[bf][i] = kp[i]; quf[bf][i] = qp[i]; }
        }
      }

      lds_barrier();  // partials visible

      // combine partials -> full u, p
#pragma unroll
      for (int r = 0; r < 16; r++) {
        float2 pA = part2[r][0][lane];
        float2 pB = part2[r][1][lane];
        float2 pC = part2[r][2][lane];
        float2 pD = part2[r][3][lane];
        u0[r] = (pA.x + pB.x) + (pC.x + pD.x);
        p0[r] = (pA.y + pB.y) + (pC.y + pD.y);
      }

      // ---- phase B: 16 serial steps, no barriers ----
#pragma unroll
      for (int t = 0; t < 16; t++) {
        float u = u0[t];
        float kcur = krow[t], vcur = vrow[t], qcur = qrow[t];
        float ecur = RL(ev, cc * 16 + t);
        float c0 = g * (kcur + bet - vcur);

        float Su   = wave_allsum(u);
        float Suu  = wave_allsum(u * u);
        float Sau  = wave_allsum(a * u);
        float Sauu = wave_allsum(a * u * u);
        float Scu  = wave_allsum(c0 * u);
        float Sc   = RL(SCv, t);

        float mu = Su * (1.0f / 64);
        float var = Suu * (1.0f / 64) - mu * mu;
        float rstd = rsqrtf(var + 1e-6f);
        float xh = (u - mu) * rstd;
        float Axh   = rstd * (Sau - mu * A2);
        float Scxh  = rstd * (Scu - mu * Sc);
        float Saxh2 = rstd * rstd * (Sauu - 2.0f * mu * Sau + mu * mu * A2);
        float s1 = (2.0f / 64) * (Sc + Axh);
        float s2 = (2.0f / 64) * (Scxh + Saxh2);
        float dxh = (2.0f / 64) * (c0 + a * xh);
        float dldu = rstd * (dxh - s1 * (1.0f / 64) - xh * (s2 * (1.0f / 64)));
        float coef = -ecur * dldu;

        // critical correction first: u for step t+1
        if (t < 15)
          u0[t + 1] += coef * RL(KKr[t], t + 1);
        // lazy corrections (off critical path)
#pragma unroll
        for (int s = t + 2; s < 16; s++)
          u0[s] += coef * RL(KKr[t], s);
#pragma unroll
        for (int s = t; s < 16; s++)
          p0[s] += coef * RL(KQr[t], s);

        // W-slice update via uniform LDS read of row t (off critical path;
        // next use of w is next chunk's phase A)
        {
          const float4* kp = (const float4*)&kls[t][wvu * 16];
#pragma unroll
          for (int i = 0; i < 4; i++) {
            float4 k4 = kp[i];
            w[4 * i + 0] += coef * k4.x;
            w[4 * i + 1] += coef * k4.y;
            w[4 * i + 2] += coef * k4.z;
            w[4 * i + 3] += coef * k4.w;
          }
        }

        if ((t & 3) == wvu) { u2sv[t >> 2] = p0[t]; qsv[t >> 2] = qcur; }

        // reload row t for the NEXT chunk (per-lane; 16 steps of cover)
        krow[t] = Kin[base + 16 * BD + lane];
        qrow[t] = Qin[base + 16 * BD + lane];
        vrow[t] = Vin[base + 16 * BD + lane];
        base += BD;
      }

      // ---- deferred phase-2 flush: each wave finalizes its 4 owned steps --
#pragma unroll
      for (int fi = 0; fi < 4; fi++) {
        float u2 = u2sv[fi];
        float Su2  = wave_allsum(u2);
        float Suu2 = wave_allsum(u2 * u2);
        float mu2 = Su2 * (1.0f / 64);
        float rstd2 = rsqrtf(Suu2 * (1.0f / 64) - mu2 * mu2 + 1e-6f);
        int tt = 4 * fi + wvu;
        Hout[base - (size_t)(16 - tt) * BD + lane] =
            qsv[fi] + (u2 - mu2) * rstd2 * g + bet;
      }

      // protect kls/qls/part2 (single-buffered) against next chunk's writes
      lds_barrier();
    }
    ev = evn; evn = ev2;
  }
}

// ---------------- out projection: z = H @ Wo + bo ----------------
// FROZEN (r14): 32 rows/block, measured win; accumulation order preserved.
__global__ __launch_bounds__(256) void outproj_kernel(
    const float* __restrict__ H, const float* __restrict__ Wo,
    const float* __restrict__ bo, float* __restrict__ out) {
  __shared__ __align__(16) float ht[32 * BD];  // 8 KB
  const int tid = threadIdx.x;
  const size_t row0 = (size_t)blockIdx.x * 32;
#pragma unroll
  for (int i = 0; i < 2; i++)
    ((float4*)ht)[i * 256 + tid] = ((const float4*)(H + row0 * BD))[i * 256 + tid];
  __syncthreads();
  float acc0[32], acc1[32];
#pragma unroll
  for (int r = 0; r < 32; r++) { acc0[r] = 0.f; acc1[r] = 0.f; }
  for (int kk4 = 0; kk4 < 16; kk4++) {
    float w00 = Wo[(4 * kk4 + 0) * D + tid];
    float w01 = Wo[(4 * kk4 + 1) * D + tid];
    float w02 = Wo[(4 * kk4 + 2) * D + tid];
    float w03 = Wo[(4 * kk4 + 3) * D + tid];
    float w10 = Wo[(4 * kk4 + 0) * D + tid + 256];
    float w11 = Wo[(4 * kk4 + 1) * D + tid + 256];
    float w12 = Wo[(4 * kk4 + 2) * D + tid + 256];
    float w13 = Wo[(4 * kk4 + 3) * D + tid + 256];
#pragma unroll
    for (int r = 0; r < 32; r++) {
      float4 hv = *(const float4*)&ht[r * BD + 4 * kk4];
      acc0[r] += hv.x * w00;
      acc0[r] += hv.y * w01;
      acc0[r] += hv.z * w02;
      acc0[r] += hv.w * w03;
      acc1[r] += hv.x * w10;
      acc1[r] += hv.y * w11;
      acc1[r] += hv.z * w12;
      acc1[r] += hv.w * w13;
    }
  }
  float b0 = bo[tid], b1 = bo[tid + 256];
#pragma unroll
  for (int r = 0; r < 32; r++) {
    out[(row0 + r) * D + tid] = acc0[r] + b0;
    out[(row0 + r) * D + tid + 256] = acc1[r] + b1;
  }
}

extern "C" void kernel_launch(void* const* d_in, const int* in_sizes, int n_in,
                              void* d_out, int out_size, void* d_ws,
                              size_t ws_size, hipStream_t stream) {
  (void)in_sizes; (void)n_in; (void)out_size; (void)ws_size;
  const float* x    = (const float*)d_in[0];
  const float* Wk   = (const float*)d_in[1];
  const float* bk   = (const float*)d_in[2];
  const float* Wv   = (const float*)d_in[3];
  const float* bv   = (const float*)d_in[4];
  const float* Wq   = (const float*)d_in[5];
  const float* bq   = (const float*)d_in[6];
  const float* Wo   = (const float*)d_in[7];
  const float* bo   = (const float*)d_in[8];
  const float* ln_g = (const float*)d_in[9];
  const float* ln_b = (const float*)d_in[10];
  const float* lr_w = (const float*)d_in[11];
  const float* lr_b = (const float*)d_in[12];
  const float* W0   = (const float*)d_in[13];

  float* ws  = (float*)d_ws;
  float* Kb  = ws + OFF_K;
  float* Vb  = ws + OFF_V;
  float* Qb  = ws + OFF_Q;
  float* ETA = ws + OFF_ETA;
  float* Hb  = ws + OFF_H;
  float* out = (float*)d_out;
  float* GRAM = out;  // scratch inside d_out; overwritten later by outproj

  proj_kernel<<<NCHUNK, 256, 0, stream>>>(x, Wk, bk, Wv, bv, Wq, bq,
                                          lr_w, lr_b, ln_g, ln_b,
                                          Kb, Vb, Qb, ETA, GRAM);
  ttt_seq_kernel<<<NB, 256, 0, stream>>>(Kb, Vb, Qb, ETA, W0, ln_g, ln_b, Hb, GRAM);
  outproj_kernel<<<BT / 32, 256, 0, stream>>>(Hb, Wo, bo, out);
}

// Round 13
// 1385.392 us; speedup vs baseline: 1.0602x; 1.0602x over previous
//
#include <hip/hip_runtime.h>
#include <math.h>

#define NB 16
#define T  2048
#define D  512
#define BD 64
#define BT (NB*T)  // 32768

// workspace layout (float offsets)
#define OFF_K   0
#define OFF_V   (BT*BD)
#define OFF_Q   (2*BT*BD)
#define OFF_ETA (3*BT*BD)
#define OFF_H   (3*BT*BD + BT)
// total floats = 4*BT*BD + BT = 8,421,376  (~33.7 MB)

// gram scratch lives in d_out (64 MB; overwritten later by outproj):
// per 16-step chunk: KK[16*16] | KQ[16*16] | SC[16] | pad -> 544 floats
#define GSTRIDE 544
#define NCHUNK  (BT/16)   // 2048

#define RL(x, i) __int_as_float(__builtin_amdgcn_readlane(__float_as_int(x), (i)))

// ---------------- DPP full-wave sum, result broadcast to all lanes ----------
__device__ __forceinline__ float wave_allsum(float x) {
  x += __int_as_float(__builtin_amdgcn_update_dpp(
      0, __float_as_int(x), 0x111, 0xf, 0xf, true));   // row_shr:1
  x += __int_as_float(__builtin_amdgcn_update_dpp(
      0, __float_as_int(x), 0x112, 0xf, 0xf, true));   // row_shr:2
  x += __int_as_float(__builtin_amdgcn_update_dpp(
      0, __float_as_int(x), 0x114, 0xf, 0xf, true));   // row_shr:4
  x += __int_as_float(__builtin_amdgcn_update_dpp(
      0, __float_as_int(x), 0x118, 0xf, 0xf, true));   // row_shr:8
  x += __int_as_float(__builtin_amdgcn_update_dpp(
      0, __float_as_int(x), 0x142, 0xa, 0xf, false));  // row_bcast:15 -> rows 1,3
  x += __int_as_float(__builtin_amdgcn_update_dpp(
      0, __float_as_int(x), 0x143, 0xc, 0xf, false));  // row_bcast:31 -> rows 2,3
  return RL(x, 63);
}

// DS-only barrier: waits lgkmcnt(0) (all loop lgkm ops are DS), leaves vmcnt
// in flight. Proven r3/r4.
__device__ __forceinline__ void lds_barrier() {
  __builtin_amdgcn_sched_barrier(0);
  __builtin_amdgcn_s_waitcnt(0xC07F);  // vmcnt=63 (no wait), expcnt=7, lgkmcnt=0
  __builtin_amdgcn_s_barrier();
  __builtin_amdgcn_sched_barrier(0);
}

// -------- fused projection + eta + gram (FROZEN r13 form; r15's LDS-drop
// variant regressed ~90us: wave-uniform global x loads repeated per-lane are
// NOT cheaper than LDS-broadcast reads; occupancy was not the constraint) ---
__global__ __launch_bounds__(256) void proj_kernel(
    const float* __restrict__ x,
    const float* __restrict__ Wk, const float* __restrict__ bk,
    const float* __restrict__ Wv, const float* __restrict__ bv,
    const float* __restrict__ Wq, const float* __restrict__ bq,
    const float* __restrict__ lr_w, const float* __restrict__ lr_b,
    const float* __restrict__ ln_g, const float* __restrict__ ln_b,
    float* __restrict__ Kout, float* __restrict__ Vout,
    float* __restrict__ Qout, float* __restrict__ eta,
    float* __restrict__ G) {
  __shared__ __align__(16) float xs[16 * D];               // 32 KB
  __shared__ __align__(16) float sK[16][64], sQ[16][64], sV[16][64];  // 12 KB
  __shared__ float sg[64], sb[64];
  const int tid = threadIdx.x;
  const size_t row0 = (size_t)blockIdx.x * 16;
  const float4* xg = (const float4*)(x + row0 * D);
  float4* xs4 = (float4*)xs;
#pragma unroll
  for (int i = 0; i < 8; i++) xs4[i * 256 + tid] = xg[i * 256 + tid];
  if (tid < 64) { sg[tid] = ln_g[tid]; sb[tid] = ln_b[tid]; }
  __syncthreads();
  const int col = tid & 63;
  const int rg = tid >> 6;  // 4 row-groups of 4 rows
  const int lane = tid & 63;

  float ak0 = 0.f, ak1 = 0.f, ak2 = 0.f, ak3 = 0.f;
  float av0 = 0.f, av1 = 0.f, av2 = 0.f, av3 = 0.f;
  float aq0 = 0.f, aq1 = 0.f, aq2 = 0.f, aq3 = 0.f;
  for (int d = 0; d < D; d += 4) {
    float wk0 = Wk[(d + 0) * BD + col];
    float wk1 = Wk[(d + 1) * BD + col];
    float wk2 = Wk[(d + 2) * BD + col];
    float wk3 = Wk[(d + 3) * BD + col];
    float wv0 = Wv[(d + 0) * BD + col];
    float wv1 = Wv[(d + 1) * BD + col];
    float wv2 = Wv[(d + 2) * BD + col];
    float wv3 = Wv[(d + 3) * BD + col];
    float wq0 = Wq[(d + 0) * BD + col];
    float wq1 = Wq[(d + 1) * BD + col];
    float wq2 = Wq[(d + 2) * BD + col];
    float wq3 = Wq[(d + 3) * BD + col];
    const float* xb = xs + (rg * 4) * D + d;
    float4 x0 = *(const float4*)(xb);
    float4 x1 = *(const float4*)(xb + D);
    float4 x2 = *(const float4*)(xb + 2 * D);
    float4 x3 = *(const float4*)(xb + 3 * D);
    ak0 += x0.x * wk0 + x0.y * wk1 + x0.z * wk2 + x0.w * wk3;
    ak1 += x1.x * wk0 + x1.y * wk1 + x1.z * wk2 + x1.w * wk3;
    ak2 += x2.x * wk0 + x2.y * wk1 + x2.z * wk2 + x2.w * wk3;
    ak3 += x3.x * wk0 + x3.y * wk1 + x3.z * wk2 + x3.w * wk3;
    av0 += x0.x * wv0 + x0.y * wv1 + x0.z * wv2 + x0.w * wv3;
    av1 += x1.x * wv0 + x1.y * wv1 + x1.z * wv2 + x1.w * wv3;
    av2 += x2.x * wv0 + x2.y * wv1 + x2.z * wv2 + x2.w * wv3;
    av3 += x3.x * wv0 + x3.y * wv1 + x3.z * wv2 + x3.w * wv3;
    aq0 += x0.x * wq0 + x0.y * wq1 + x0.z * wq2 + x0.w * wq3;
    aq1 += x1.x * wq0 + x1.y * wq1 + x1.z * wq2 + x1.w * wq3;
    aq2 += x2.x * wq0 + x2.y * wq1 + x2.z * wq2 + x2.w * wq3;
    aq3 += x3.x * wq0 + x3.y * wq1 + x3.z * wq2 + x3.w * wq3;
  }
  float bbk = bk[col], bbv = bv[col], bbq = bq[col];
  const size_t r0 = row0 + rg * 4;
  float k0v = ak0 + bbk, k1v = ak1 + bbk, k2v = ak2 + bbk, k3v = ak3 + bbk;
  float v0v = av0 + bbv, v1v = av1 + bbv, v2v = av2 + bbv, v3v = av3 + bbv;
  float q0v = aq0 + bbq, q1v = aq1 + bbq, q2v = aq2 + bbq, q3v = aq3 + bbq;
  Kout[(r0 + 0) * BD + col] = k0v;
  Kout[(r0 + 1) * BD + col] = k1v;
  Kout[(r0 + 2) * BD + col] = k2v;
  Kout[(r0 + 3) * BD + col] = k3v;
  Vout[(r0 + 0) * BD + col] = v0v;
  Vout[(r0 + 1) * BD + col] = v1v;
  Vout[(r0 + 2) * BD + col] = v2v;
  Vout[(r0 + 3) * BD + col] = v3v;
  Qout[(r0 + 0) * BD + col] = q0v;
  Qout[(r0 + 1) * BD + col] = q1v;
  Qout[(r0 + 2) * BD + col] = q2v;
  Qout[(r0 + 3) * BD + col] = q3v;
  // stage K/V/Q tile to LDS for the gram phase
  const int lr = rg * 4;
  sK[lr + 0][col] = k0v; sK[lr + 1][col] = k1v;
  sK[lr + 2][col] = k2v; sK[lr + 3][col] = k3v;
  sV[lr + 0][col] = v0v; sV[lr + 1][col] = v1v;
  sV[lr + 2][col] = v2v; sV[lr + 3][col] = v3v;
  sQ[lr + 0][col] = q0v; sQ[lr + 1][col] = q1v;
  sQ[lr + 2][col] = q2v; sQ[lr + 3][col] = q3v;

  // ---- eta for this wave's 4 rows (identical math to old eta_kernel) ----
  {
    const float* lw = lr_w + lane * 8;
    float4 la = *(const float4*)lw;
    float4 lb = *(const float4*)(lw + 4);
    float lrb0 = lr_b[0];
#pragma unroll
    for (int j = 0; j < 4; j++) {
      const float* xr = xs + (size_t)(rg * 4 + j) * D + lane * 8;
      float4 a = *(const float4*)xr;
      float4 b2 = *(const float4*)(xr + 4);
      float p = a.x * la.x + a.y * la.y + a.z * la.z + a.w * la.w +
                b2.x * lb.x + b2.y * lb.y + b2.z * lb.z + b2.w * lb.w;
#pragma unroll
      for (int m = 32; m > 0; m >>= 1) p += __shfl_xor(p, m, 64);
      if (lane == 0) eta[row0 + rg * 4 + j] = 1.0f / (1.0f + expf(-(p + lrb0)));
    }
  }
  __syncthreads();

  // ---- gram phase: bit-identical to the old standalone gram_kernel ----
  const int gi = tid >> 4, gt = tid & 15;
  float kk = 0.f, kq = 0.f;
#pragma unroll
  for (int d = 0; d < 64; d += 4) {
    float4 a4 = *(const float4*)&sK[gi][d];
    float4 b4 = *(const float4*)&sK[gt][d];
    float4 c4 = *(const float4*)&sQ[gt][d];
    kk += a4.x * b4.x + a4.y * b4.y + a4.z * b4.z + a4.w * b4.w;
    kq += a4.x * c4.x + a4.y * c4.y + a4.z * c4.z + a4.w * c4.w;
  }
  size_t gb = (size_t)blockIdx.x * GSTRIDE;
  G[gb + gi * 16 + gt] = kk;
  G[gb + 256 + gi * 16 + gt] = kq;
  if (tid < 16) {
    float sc = 0.f;
    for (int d = 0; d < 64; d++)
      sc += sg[d] * (sK[tid][d] + sb[d] - sV[tid][d]);
    G[gb + 512 + tid] = sc;
  }
}

// ---------------- sequential TTT scan: chunked delta-rule, 4 waves --------
// FROZEN: exact r4 structure, measured 1096/1096/1094/1095/1095us across
// five runs. Five structural variants (r5-r8, r11) all regressed; do not touch.
__global__ __launch_bounds__(256, 1)
void ttt_seq_kernel(
    const float* __restrict__ Kin, const float* __restrict__ Vin,
    const float* __restrict__ Qin, const float* __restrict__ eta_in,
    const float* __restrict__ W0, const float* __restrict__ ln_g,
    const float* __restrict__ ln_b, float* __restrict__ Hout,
    const float* __restrict__ gram) {
  __shared__ __align__(16) float2 part2[16][4][64];  // 32 KB partials
  __shared__ __align__(16) float kls[16][64];        // 4 KB k rows
  __shared__ __align__(16) float qls[16][64];        // 4 KB q rows
  const int tid = threadIdx.x;
  const int lane = tid & 63;
  const int wvu = __builtin_amdgcn_readfirstlane(tid) >> 6;
  const int b = blockIdx.x;

  // W slice: w[4i+j] = W0[lane*BD + 16*wvu + 4i+j]
  float w[16];
  {
    const float4* w04 = (const float4*)(W0 + (size_t)lane * BD + wvu * 16);
#pragma unroll
    for (int i = 0; i < 4; i++) {
      float4 t4 = w04[i];
      w[4 * i] = t4.x; w[4 * i + 1] = t4.y; w[4 * i + 2] = t4.z; w[4 * i + 3] = t4.w;
    }
  }
  const float g = ln_g[lane];
  const float bet = ln_b[lane];
  const float a = g * g;
  const float A2 = wave_allsum(a);

  size_t base = (size_t)b * T * BD;   // advances BD per step
  size_t ebase = (size_t)b * T;

  // per-lane rows of the current chunk (reloaded in-place for chunk+1 during
  // phase B, period-16 ring -> zero extra registers)
  float krow[16], qrow[16], vrow[16];
#pragma unroll
  for (int r = 0; r < 16; r++) {
    krow[r] = Kin[base + r * BD + lane];
    qrow[r] = Qin[base + r * BD + lane];
    vrow[r] = Vin[base + r * BD + lane];
  }
  float ev  = eta_in[ebase + lane];
  float evn = eta_in[ebase + 64 + lane];

  float u2sv[4], qsv[4];  // deferred phase-2 state (4 owned steps per wave)

  for (int c64 = 0; c64 < 32; c64++) {
    size_t eoff = (size_t)(c64 + 2) * 64;
    if (eoff >= T) eoff = 0;
    float ev2 = eta_in[ebase + eoff + lane];

    for (int cc = 0; cc < 4; cc++) {
      // ---- gram loads for this chunk (consumed in phase B; phase A covers) --
      const size_t gb = (size_t)(b * 128 + c64 * 4 + cc) * GSTRIDE;
      float KKr[15], KQr[16];
#pragma unroll
      for (int t = 0; t < 15; t++) KKr[t] = gram[gb + t * 16 + lane];
#pragma unroll
      for (int t = 0; t < 16; t++) KQr[t] = gram[gb + 256 + t * 16 + lane];
      float SCv = gram[gb + 512 + lane];

      // ---- phase A: stage rows to LDS (all waves write identical values:
      // benign; each wave's own in-order DS writes make its reads correct) --
#pragma unroll
      for (int r = 0; r < 16; r++) {
        kls[r][lane] = krow[r];
        qls[r][lane] = qrow[r];
      }
      // 3-deep uniform-read pipeline (broadcast ds_read_b128, conflict-free)
      float4 kuf[3][4], quf[3][4];
#pragma unroll
      for (int r = 0; r < 3; r++) {
        const float4* kp = (const float4*)&kls[r][wvu * 16];
        const float4* qp = (const float4*)&qls[r][wvu * 16];
#pragma unroll
        for (int i = 0; i < 4; i++) { kuf[r][i] = kp[i]; quf[r][i] = qp[i]; }
      }
      float u0[16], p0[16];
#pragma unroll
      for (int r = 0; r < 16; r++) {
        const int bf = r % 3;
        float uu0 = 0.f, uu1 = 0.f, uu2 = 0.f, uu3 = 0.f;
        float pp0 = 0.f, pp1 = 0.f, pp2 = 0.f, pp3 = 0.f;
#pragma unroll
        for (int i = 0; i < 4; i++) {
          uu0 += kuf[bf][i].x * w[4 * i + 0];
          uu1 += kuf[bf][i].y * w[4 * i + 1];
          uu2 += kuf[bf][i].z * w[4 * i + 2];
          uu3 += kuf[bf][i].w * w[4 * i + 3];
          pp0 += quf[bf][i].x * w[4 * i + 0];
          pp1 += quf[bf][i].y * w[4 * i + 1];
          pp2 += quf[bf][i].z * w[4 * i + 2];
          pp3 += quf[bf][i].w * w[4 * i + 3];
        }
        part2[r][wvu][lane] = make_float2((uu0 + uu1) + (uu2 + uu3),
                                          (pp0 + pp1) + (pp2 + pp3));
        if (r < 13) {
          const float4* kp = (const float4*)&kls[r + 3][wvu * 16];
          const float4* qp = (const float4*)&qls[r + 3][wvu * 16];
#pragma unroll
          for (int i = 0; i < 4; i++) { kuf[bf][i] = kp[i]; quf[bf][i] = qp[i]; }
        }
      }

      lds_barrier();  // partials visible

      // combine partials -> full u, p
#pragma unroll
      for (int r = 0; r < 16; r++) {
        float2 pA = part2[r][0][lane];
        float2 pB = part2[r][1][lane];
        float2 pC = part2[r][2][lane];
        float2 pD = part2[r][3][lane];
        u0[r] = (pA.x + pB.x) + (pC.x + pD.x);
        p0[r] = (pA.y + pB.y) + (pC.y + pD.y);
      }

      // ---- phase B: 16 serial steps, no barriers ----
#pragma unroll
      for (int t = 0; t < 16; t++) {
        float u = u0[t];
        float kcur = krow[t], vcur = vrow[t], qcur = qrow[t];
        float ecur = RL(ev, cc * 16 + t);
        float c0 = g * (kcur + bet - vcur);

        float Su   = wave_allsum(u);
        float Suu  = wave_allsum(u * u);
        float Sau  = wave_allsum(a * u);
        float Sauu = wave_allsum(a * u * u);
        float Scu  = wave_allsum(c0 * u);
        float Sc   = RL(SCv, t);

        float mu = Su * (1.0f / 64);
        float var = Suu * (1.0f / 64) - mu * mu;
        float rstd = rsqrtf(var + 1e-6f);
        float xh = (u - mu) * rstd;
        float Axh   = rstd * (Sau - mu * A2);
        float Scxh  = rstd * (Scu - mu * Sc);
        float Saxh2 = rstd * rstd * (Sauu - 2.0f * mu * Sau + mu * mu * A2);
        float s1 = (2.0f / 64) * (Sc + Axh);
        float s2 = (2.0f / 64) * (Scxh + Saxh2);
        float dxh = (2.0f / 64) * (c0 + a * xh);
        float dldu = rstd * (dxh - s1 * (1.0f / 64) - xh * (s2 * (1.0f / 64)));
        float coef = -ecur * dldu;

        // critical correction first: u for step t+1
        if (t < 15)
          u0[t + 1] += coef * RL(KKr[t], t + 1);
        // lazy corrections (off critical path)
#pragma unroll
        for (int s = t + 2; s < 16; s++)
          u0[s] += coef * RL(KKr[t], s);
#pragma unroll
        for (int s = t; s < 16; s++)
          p0[s] += coef * RL(KQr[t], s);

        // W-slice update via uniform LDS read of row t (off critical path;
        // next use of w is next chunk's phase A)
        {
          const float4* kp = (const float4*)&kls[t][wvu * 16];
#pragma unroll
          for (int i = 0; i < 4; i++) {
            float4 k4 = kp[i];
            w[4 * i + 0] += coef * k4.x;
            w[4 * i + 1] += coef * k4.y;
            w[4 * i + 2] += coef * k4.z;
            w[4 * i + 3] += coef * k4.w;
          }
        }

        if ((t & 3) == wvu) { u2sv[t >> 2] = p0[t]; qsv[t >> 2] = qcur; }

        // reload row t for the NEXT chunk (per-lane; 16 steps of cover)
        krow[t] = Kin[base + 16 * BD + lane];
        qrow[t] = Qin[base + 16 * BD + lane];
        vrow[t] = Vin[base + 16 * BD + lane];
        base += BD;
      }

      // ---- deferred phase-2 flush: each wave finalizes its 4 owned steps --
#pragma unroll
      for (int fi = 0; fi < 4; fi++) {
        float u2 = u2sv[fi];
        float Su2  = wave_allsum(u2);
        float Suu2 = wave_allsum(u2 * u2);
        float mu2 = Su2 * (1.0f / 64);
        float rstd2 = rsqrtf(Suu2 * (1.0f / 64) - mu2 * mu2 + 1e-6f);
        int tt = 4 * fi + wvu;
        Hout[base - (size_t)(16 - tt) * BD + lane] =
            qsv[fi] + (u2 - mu2) * rstd2 * g + bet;
      }

      // protect kls/qls/part2 (single-buffered) against next chunk's writes
      lds_barrier();
    }
    ev = evn; evn = ev2;
  }
}

// ---------------- out projection: z = H @ Wo + bo ----------------
// FROZEN (r14): 32 rows/block, measured win; accumulation order preserved.
__global__ __launch_bounds__(256) void outproj_kernel(
    const float* __restrict__ H, const float* __restrict__ Wo,
    const float* __restrict__ bo, float* __restrict__ out) {
  __shared__ __align__(16) float ht[32 * BD];  // 8 KB
  const int tid = threadIdx.x;
  const size_t row0 = (size_t)blockIdx.x * 32;
#pragma unroll
  for (int i = 0; i < 2; i++)
    ((float4*)ht)[i * 256 + tid] = ((const float4*)(H + row0 * BD))[i * 256 + tid];
  __syncthreads();
  float acc0[32], acc1[32];
#pragma unroll
  for (int r = 0; r < 32; r++) { acc0[r] = 0.f; acc1[r] = 0.f; }
  for (int kk4 = 0; kk4 < 16; kk4++) {
    float w00 = Wo[(4 * kk4 + 0) * D + tid];
    float w01 = Wo[(4 * kk4 + 1) * D + tid];
    float w02 = Wo[(4 * kk4 + 2) * D + tid];
    float w03 = Wo[(4 * kk4 + 3) * D + tid];
    float w10 = Wo[(4 * kk4 + 0) * D + tid + 256];
    float w11 = Wo[(4 * kk4 + 1) * D + tid + 256];
    float w12 = Wo[(4 * kk4 + 2) * D + tid + 256];
    float w13 = Wo[(4 * kk4 + 3) * D + tid + 256];
#pragma unroll
    for (int r = 0; r < 32; r++) {
      float4 hv = *(const float4*)&ht[r * BD + 4 * kk4];
      acc0[r] += hv.x * w00;
      acc0[r] += hv.y * w01;
      acc0[r] += hv.z * w02;
      acc0[r] += hv.w * w03;
      acc1[r] += hv.x * w10;
      acc1[r] += hv.y * w11;
      acc1[r] += hv.z * w12;
      acc1[r] += hv.w * w13;
    }
  }
  float b0 = bo[tid], b1 = bo[tid + 256];
#pragma unroll
  for (int r = 0; r < 32; r++) {
    out[(row0 + r) * D + tid] = acc0[r] + b0;
    out[(row0 + r) * D + tid + 256] = acc1[r] + b1;
  }
}

extern "C" void kernel_launch(void* const* d_in, const int* in_sizes, int n_in,
                              void* d_out, int out_size, void* d_ws,
                              size_t ws_size, hipStream_t stream) {
  (void)in_sizes; (void)n_in; (void)out_size; (void)ws_size;
  const float* x    = (const float*)d_in[0];
  const float* Wk   = (const float*)d_in[1];
  const float* bk   = (const float*)d_in[2];
  const float* Wv   = (const float*)d_in[3];
  const float* bv   = (const float*)d_in[4];
  const float* Wq   = (const float*)d_in[5];
  const float* bq   = (const float*)d_in[6];
  const float* Wo   = (const float*)d_in[7];
  const float* bo   = (const float*)d_in[8];
  const float* ln_g = (const float*)d_in[9];
  const float* ln_b = (const float*)d_in[10];
  const float* lr_w = (const float*)d_in[11];
  const float* lr_b = (const float*)d_in[12];
  const float* W0   = (const float*)d_in[13];

  float* ws  = (float*)d_ws;
  float* Kb  = ws + OFF_K;
  float* Vb  = ws + OFF_V;
  float* Qb  = ws + OFF_Q;
  float* ETA = ws + OFF_ETA;
  float* Hb  = ws + OFF_H;
  float* out = (float*)d_out;
  float* GRAM = out;  // scratch inside d_out; overwritten later by outproj

  proj_kernel<<<NCHUNK, 256, 0, stream>>>(x, Wk, bk, Wv, bv, Wq, bq,
                                          lr_w, lr_b, ln_g, ln_b,
                                          Kb, Vb, Qb, ETA, GRAM);
  ttt_seq_kernel<<<NB, 256, 0, stream>>>(Kb, Vb, Qb, ETA, W0, ln_g, ln_b, Hb, GRAM);
  outproj_kernel<<<BT / 32, 256, 0, stream>>>(Hb, Wo, bo, out);
}